// Round 3
// baseline (468.744 us; speedup 1.0000x reference)
//
#include <hip/hip_runtime.h>
#include <stdint.h>

// Titans-L2 chunked delta-rule forward.
// Pipeline:
//   1. cast x -> bf16; transpose+cast Wq/Wk/Wv/Wo -> bf16 [N,K] (B^T form)
//   2. MFMA GEMMs: q,k,v = x@W  (written in [B,H,T,D] f32 layout)
//   3. chunk_op: per lane n=(b,h,c): A = prod(I - a k k^T), B accumulation
//      (k normalized during LDS staging via DPP rotate-reduce; quad_perm DPP
//       j-reduction -> no LDS-pipe shuffles in the 128-step scan)
//   4. chunk_scan: M_{c+1} = M_c A_c + B_c over 16 chunks; emits Mstart + M_final(out)
//   5. chunk_proc: y_t = M q_t with rank-1 M updates; writes y directly as
//      bf16 [B*T, C] (fused cast + layout transform)
//   6. final MFMA GEMM y@Wo -> d_out
// Dims: B=4 H=16 T=2048 C=1024 D=64 CS=128 nc=16 N=1024 tokens=8192

#define DEV __device__ __forceinline__

typedef __attribute__((ext_vector_type(4))) float f32x4;
typedef __attribute__((ext_vector_type(8))) __bf16 bf16x8;
typedef __attribute__((ext_vector_type(4))) __bf16 bf16x4;

typedef const __attribute__((address_space(1))) uint32_t* gas1_t;
typedef __attribute__((address_space(3))) uint32_t* las3_t;

DEV void gload_lds16(const void* g, void* l) {
  __builtin_amdgcn_global_load_lds((gas1_t)g, (las3_t)l, 16, 0, 0);
}

DEV float sgm(float x) { return 1.f / (1.f + __expf(-x)); }

// ---- DPP cross-lane helpers (pure VALU, no LDS pipe) ----
template <int CTRL>
DEV float dpp_mov(float x) {
  return __builtin_bit_cast(
      float, __builtin_amdgcn_mov_dpp(__builtin_bit_cast(int, x), CTRL, 0xF, 0xF, true));
}
// sum over the 4 lanes of a quad (j = lane&3)
DEV float quad_reduce(float x) {
  x += dpp_mov<0xB1>(x);  // quad_perm(1,0,3,2) == xor1
  x += dpp_mov<0x4E>(x);  // quad_perm(2,3,0,1) == xor2
  return x;
}
// cyclic rotate-reduce: sum over each 16-lane DPP row
DEV float row16_reduce(float x) {
  x += dpp_mov<0x121>(x);  // row_ror:1
  x += dpp_mov<0x122>(x);  // row_ror:2
  x += dpp_mov<0x124>(x);  // row_ror:4
  x += dpp_mov<0x128>(x);  // row_ror:8
  return x;
}

// ---------------- casts ----------------
__global__ __launch_bounds__(256) void cast_f32_bf16(const float* __restrict__ in,
                                                     __bf16* __restrict__ out) {
  int idx = blockIdx.x * 256 + threadIdx.x;
  float4 v = ((const float4*)in)[idx];
  bf16x4 o;
  o[0] = (__bf16)v.x; o[1] = (__bf16)v.y; o[2] = (__bf16)v.z; o[3] = (__bf16)v.w;
  ((bf16x4*)out)[idx] = o;
}

// W [K=1024][N=1024] f32 -> Wt [N][K] bf16
__global__ __launch_bounds__(256) void transpose_cast(const float* __restrict__ W,
                                                      __bf16* __restrict__ Wt) {
  __shared__ float tile[32][33];
  int tx = threadIdx.x & 31, ty = threadIdx.x >> 5;
  int n0 = blockIdx.x * 32, k0 = blockIdx.y * 32;
#pragma unroll
  for (int u = 0; u < 4; ++u)
    tile[ty + u * 8][tx] = W[(size_t)(k0 + ty + u * 8) * 1024 + n0 + tx];
  __syncthreads();
#pragma unroll
  for (int u = 0; u < 4; ++u)
    Wt[(size_t)(n0 + ty + u * 8) * 1024 + k0 + tx] = (__bf16)tile[tx][ty + u * 8];
}

// ---------------- GEMM: C[M=8192,N=1024] = A[M,K=1024] * Bt[N,K]^T ----------------
// 128x128 tile, BK=32, 4 waves, 16x16x32 bf16 MFMA, global_load_lds staging.
// mode 0: C row-major [M,1024]. mode 1: scatter to [B,H,T,D] (row=token, col=h*64+d)
__global__ __launch_bounds__(256) void gemm_bt(const __bf16* __restrict__ A,
                                               const __bf16* __restrict__ Bt,
                                               float* __restrict__ C, int mode) {
  const int t = threadIdx.x;
  const int wv = t >> 6, lane = t & 63;
  const int bm = blockIdx.y, bn = blockIdx.x;
  const int K = 1024;
  __shared__ __bf16 lA[4096];
  __shared__ __bf16 lB[4096];
  f32x4 acc[4][4];
#pragma unroll
  for (int m = 0; m < 4; ++m)
#pragma unroll
    for (int n = 0; n < 4; ++n) acc[m][n] = 0.f;
  const int wr = wv >> 1, wc = wv & 1;
  const int fr = lane & 15, fk = (lane >> 4) * 8;
  const int e0 = (wv * 128 + lane) * 8;
  const int e1 = (wv * 128 + 64 + lane) * 8;
  const int r0s = e0 >> 5, c0s = e0 & 31;
  const int r1s = e1 >> 5, c1s = e1 & 31;
  for (int k0 = 0; k0 < K; k0 += 32) {
    gload_lds16(A + (size_t)(bm * 128 + r0s) * K + k0 + c0s, lA + wv * 1024);
    gload_lds16(Bt + (size_t)(bn * 128 + r0s) * K + k0 + c0s, lB + wv * 1024);
    gload_lds16(A + (size_t)(bm * 128 + r1s) * K + k0 + c1s, lA + wv * 1024 + 512);
    gload_lds16(Bt + (size_t)(bn * 128 + r1s) * K + k0 + c1s, lB + wv * 1024 + 512);
    __syncthreads();
    bf16x8 af[4], bg[4];
#pragma unroll
    for (int m = 0; m < 4; ++m)
      af[m] = *(const bf16x8*)(lA + (wr * 64 + m * 16 + fr) * 32 + fk);
#pragma unroll
    for (int n = 0; n < 4; ++n)
      bg[n] = *(const bf16x8*)(lB + (wc * 64 + n * 16 + fr) * 32 + fk);
#pragma unroll
    for (int m = 0; m < 4; ++m)
#pragma unroll
      for (int n = 0; n < 4; ++n)
        acc[m][n] = __builtin_amdgcn_mfma_f32_16x16x32_bf16(af[m], bg[n], acc[m][n], 0, 0, 0);
    __syncthreads();
  }
  const int rr = (lane >> 4) * 4, cl = lane & 15;
#pragma unroll
  for (int m = 0; m < 4; ++m) {
#pragma unroll
    for (int n = 0; n < 4; ++n) {
#pragma unroll
      for (int rg = 0; rg < 4; ++rg) {
        int row = bm * 128 + wr * 64 + m * 16 + rr + rg;
        int col = bn * 128 + wc * 64 + n * 16 + cl;
        float val = acc[m][n][rg];
        if (mode == 0) {
          C[(size_t)row * 1024 + col] = val;
        } else {
          int b = row >> 11, tk = row & 2047;
          int h = col >> 6, d = col & 63;
          C[(((size_t)b * 16 + h) * 2048 + tk) * 64 + d] = val;
        }
      }
    }
  }
}

// ---------------- per-chunk operator scan (A, B) ----------------
// block = lane n (1024 blocks), 256 threads: thread (i=t>>2, j=t&3) owns
// A[i][j*16..+16), B[i][j*16..+16). k staged+normalized in LDS (DPP row
// reduce during staging); j-reduction via quad_perm DPP (no LDS shuffles).
__global__ __launch_bounds__(256, 4) void chunk_op(const float* __restrict__ k,
                                                   const float* __restrict__ v,
                                                   const float* __restrict__ ar,
                                                   const float* __restrict__ br,
                                                   float* __restrict__ Aop,
                                                   float* __restrict__ Bop) {
  int n = blockIdx.x, h = (n >> 4) & 15;
  float a = sgm(ar[h]) * 0.5f;
  float b = sgm(br[h]) * 0.5f;
  int t = threadIdx.x, i = t >> 2, j = t & 3;
  __shared__ float ks[8192];
  const float* kc = k + (size_t)n * 8192;
  const float* vc = v + (size_t)n * 8192 + i;
  // stage + normalize: 16-lane DPP row holds one k-row (16 float4 = 64 floats)
#pragma unroll
  for (int it = 0; it < 8; ++it) {
    int u = it * 256 + t;
    float4 kv = ((const float4*)kc)[u];
    float ssq = kv.x * kv.x + kv.y * kv.y + kv.z * kv.z + kv.w * kv.w;
    ssq = row16_reduce(ssq);
    float inv = 1.f / fmaxf(sqrtf(ssq), 1e-12f);
    kv.x *= inv; kv.y *= inv; kv.z *= inv; kv.w *= inv;
    ((float4*)ks)[u] = kv;
  }
  float A[16] __attribute__((aligned(16)));
  float B[16] __attribute__((aligned(16)));
#pragma unroll
  for (int u = 0; u < 16; ++u) {
    A[u] = (i == j * 16 + u) ? 1.f : 0.f;
    B[u] = 0.f;
  }
  __syncthreads();
  for (int s = 0; s < 128; ++s) {
    float kq[16] __attribute__((aligned(16)));
#pragma unroll
    for (int u = 0; u < 4; ++u)
      *(float4*)(&kq[u * 4]) = *(const float4*)(ks + s * 64 + j * 16 + u * 4);
    float ak0 = 0.f, ak1 = 0.f, bk0 = 0.f, bk1 = 0.f;
#pragma unroll
    for (int u = 0; u < 8; ++u) { ak0 += A[u] * kq[u]; bk0 += B[u] * kq[u]; }
#pragma unroll
    for (int u = 8; u < 16; ++u) { ak1 += A[u] * kq[u]; bk1 += B[u] * kq[u]; }
    float ak = quad_reduce(ak0 + ak1);
    float bk = quad_reduce(bk0 + bk1);
    float vi = vc[s * 64];
    float sA = -a * ak;
    float sB = -a * bk + b * vi;
#pragma unroll
    for (int u = 0; u < 16; ++u) { A[u] += sA * kq[u]; B[u] += sB * kq[u]; }
  }
  size_t base = (size_t)n * 4096 + i * 64 + j * 16;
#pragma unroll
  for (int u = 0; u < 4; ++u) {
    *(float4*)(Aop + base + u * 4) = *(const float4*)(&A[u * 4]);
    *(float4*)(Bop + base + u * 4) = *(const float4*)(&B[u * 4]);
  }
}

// ---------------- inter-chunk scan: M <- M*A + B ----------------
// 64 blocks (one per (b,h)), sequential over 16 chunks.
__global__ __launch_bounds__(256) void chunk_scan(const float* __restrict__ Aop,
                                                  const float* __restrict__ Bop,
                                                  float* __restrict__ Mstart,
                                                  float* __restrict__ Mfinal) {
  int bh = blockIdx.x;
  int t = threadIdx.x, i = t >> 2, qd = t & 3;
  float M[16] __attribute__((aligned(16)));
#pragma unroll
  for (int j = 0; j < 16; ++j) M[j] = 0.f;
  __shared__ float As[4096];
  for (int c = 0; c < 16; ++c) {
    size_t cb = ((size_t)bh * 16 + c) * 4096;
#pragma unroll
    for (int u = 0; u < 4; ++u)
      *(float4*)(Mstart + cb + i * 64 + qd * 16 + u * 4) = *(const float4*)(&M[u * 4]);
    __syncthreads();
    for (int u = t; u < 1024; u += 256)
      ((float4*)As)[u] = ((const float4*)(Aop + cb))[u];
    __syncthreads();
    float acc[16] __attribute__((aligned(16)));
#pragma unroll
    for (int j = 0; j < 16; ++j) acc[j] = 0.f;
#pragma unroll
    for (int l = 0; l < 64; ++l) {
      float mil = __shfl(M[l & 15], ((t >> 2) & 15) * 4 + (l >> 4), 64);
      const float* arow = As + l * 64 + qd * 16;
#pragma unroll
      for (int j = 0; j < 16; ++j) acc[j] += mil * arow[j];
    }
#pragma unroll
    for (int u = 0; u < 4; ++u) {
      float4 bv = *(const float4*)(Bop + cb + i * 64 + qd * 16 + u * 4);
      acc[u * 4 + 0] += bv.x; acc[u * 4 + 1] += bv.y;
      acc[u * 4 + 2] += bv.z; acc[u * 4 + 3] += bv.w;
    }
#pragma unroll
    for (int j = 0; j < 16; ++j) M[j] = acc[j];
  }
#pragma unroll
  for (int u = 0; u < 4; ++u)
    *(float4*)(Mfinal + (size_t)bh * 4096 + i * 64 + qd * 16 + u * 4) =
        *(const float4*)(&M[u * 4]);
}

// ---------------- intra-chunk application: y_t = M q_t ----------------
// 256 threads: thread (i=t>>2, j=t&3) owns M[i][j*16..+16). k staged+normalized
// in LDS; q,v read from global (L1 broadcast). y written directly as bf16
// [B*T, C]: row = b*2048 + c*128 + s, col = h*64 + i.
__global__ __launch_bounds__(256, 4) void chunk_proc(const float* __restrict__ q,
                                                     const float* __restrict__ k,
                                                     const float* __restrict__ v,
                                                     const float* __restrict__ Mstart,
                                                     const float* __restrict__ ar,
                                                     const float* __restrict__ br,
                                                     __bf16* __restrict__ ybf) {
  int n = blockIdx.x, h = (n >> 4) & 15;
  int b = n >> 8, c = n & 15;
  float a = sgm(ar[h]) * 0.5f;
  float bb = sgm(br[h]) * 0.5f;
  int t = threadIdx.x, i = t >> 2, j = t & 3;
  __shared__ float ks[8192];
  const float* kc = k + (size_t)n * 8192;
  const float* vc = v + (size_t)n * 8192 + i;
  const float* qc = q + (size_t)n * 8192 + j * 16;
  __bf16* yc = ybf + ((size_t)b * 2048 + c * 128) * 1024 + h * 64 + i;
#pragma unroll
  for (int it = 0; it < 8; ++it) {
    int u = it * 256 + t;
    float4 kv = ((const float4*)kc)[u];
    float ssq = kv.x * kv.x + kv.y * kv.y + kv.z * kv.z + kv.w * kv.w;
    ssq = row16_reduce(ssq);
    float inv = 1.f / fmaxf(sqrtf(ssq), 1e-12f);
    kv.x *= inv; kv.y *= inv; kv.z *= inv; kv.w *= inv;
    ((float4*)ks)[u] = kv;
  }
  float M[16] __attribute__((aligned(16)));
  {
    const float* mb = Mstart + (size_t)n * 4096 + i * 64 + j * 16;
#pragma unroll
    for (int u = 0; u < 4; ++u) *(float4*)(&M[u * 4]) = *(const float4*)(mb + u * 4);
  }
  __syncthreads();
  for (int s = 0; s < 128; ++s) {
    float kq[16] __attribute__((aligned(16)));
    float qq[16] __attribute__((aligned(16)));
#pragma unroll
    for (int u = 0; u < 4; ++u) {
      *(float4*)(&kq[u * 4]) = *(const float4*)(ks + s * 64 + j * 16 + u * 4);
      *(float4*)(&qq[u * 4]) = *(const float4*)(qc + s * 64 + u * 4);
    }
    float yp0 = 0.f, yp1 = 0.f, mk0 = 0.f, mk1 = 0.f;
#pragma unroll
    for (int u = 0; u < 8; ++u) { yp0 += M[u] * qq[u]; mk0 += M[u] * kq[u]; }
#pragma unroll
    for (int u = 8; u < 16; ++u) { yp1 += M[u] * qq[u]; mk1 += M[u] * kq[u]; }
    float yp = quad_reduce(yp0 + yp1);
    float mk = quad_reduce(mk0 + mk1);
    float vi = vc[s * 64];
    float sc = -a * mk + bb * vi;
#pragma unroll
    for (int u = 0; u < 16; ++u) M[u] += sc * kq[u];
    if (j == 0) yc[(size_t)s * 1024] = (__bf16)yp;
  }
}

extern "C" void kernel_launch(void* const* d_in, const int* in_sizes, int n_in,
                              void* d_out, int out_size, void* d_ws, size_t ws_size,
                              hipStream_t stream) {
  const float* x  = (const float*)d_in[0];
  const float* Wq = (const float*)d_in[1];
  const float* Wk = (const float*)d_in[2];
  const float* Wv = (const float*)d_in[3];
  const float* Wo = (const float*)d_in[4];
  const float* ar = (const float*)d_in[5];
  const float* br = (const float*)d_in[6];

  char* ws = (char*)d_ws;
  __bf16* xb  = (__bf16*)ws;                      // 16 MB (reused later as y_bf16)
  __bf16* wqt = (__bf16*)(ws + (16u << 20));      // 2 MB each
  __bf16* wkt = wqt + (1u << 20);
  __bf16* wvt = wkt + (1u << 20);
  __bf16* wot = wvt + (1u << 20);
  float* qb  = (float*)(ws + (24u << 20));        // 32 MB
  float* kb  = qb + (8u << 20);                   // 32 MB
  float* vb  = kb + (8u << 20);                   // 32 MB
  float* Aop = vb + (8u << 20);                   // 16 MB
  float* Bop = Aop + (4u << 20);                  // 16 MB
  float* Mst = Bop + (4u << 20);                  // 16 MB
  __bf16* ybf = xb;                               // reuse x_bf16 region

  float* yout = (float*)d_out;                    // [B*T, C] = 8,388,608 f32
  float* Mfin = yout + 8388608;                   // [B,H,D,D] = 262,144 f32

  cast_f32_bf16<<<8192, 256, 0, stream>>>(x, xb);
  dim3 tg(32, 32);
  transpose_cast<<<tg, 256, 0, stream>>>(Wq, wqt);
  transpose_cast<<<tg, 256, 0, stream>>>(Wk, wkt);
  transpose_cast<<<tg, 256, 0, stream>>>(Wv, wvt);
  transpose_cast<<<tg, 256, 0, stream>>>(Wo, wot);

  dim3 gg(8, 64);
  gemm_bt<<<gg, 256, 0, stream>>>(xb, wqt, qb, 1);
  gemm_bt<<<gg, 256, 0, stream>>>(xb, wkt, kb, 1);
  gemm_bt<<<gg, 256, 0, stream>>>(xb, wvt, vb, 1);

  chunk_op<<<1024, 256, 0, stream>>>(kb, vb, ar, br, Aop, Bop);
  chunk_scan<<<64, 256, 0, stream>>>(Aop, Bop, Mst, Mfin);
  chunk_proc<<<1024, 256, 0, stream>>>(qb, kb, vb, Mst, ar, br, ybf);

  gemm_bt<<<gg, 256, 0, stream>>>(ybf, wot, yout, 0);
}

// Round 4
// 439.105 us; speedup vs baseline: 1.0675x; 1.0675x over previous
//
#include <hip/hip_runtime.h>
#include <stdint.h>

// Titans-L2 chunked delta-rule forward.
// Pipeline:
//   1. cast x -> bf16; transpose+cast Wq/Wk/Wv/Wo -> bf16 [N,K] (B^T form)
//   2. MFMA GEMMs: q,k,v = x@W  (written in [B,H,T,D] f32 layout)
//   3. chunk_op: per lane n=(b,h,c): A = prod(I - a k k^T), B accumulation
//      512 thr (i=t>>3, j=t&7, 8 elems/thr); k normalized during LDS staging
//      (DPP row16 rotate-reduce); j-reduce = quad_perm + half_mirror DPP
//      (zero LDS-pipe shuffles in the 128-step scan)
//   4. chunk_scan: M_{c+1} = M_c A_c + B_c over 16 chunks; emits Mstart + M_final(out)
//   5. chunk_proc: y_t = M q_t with rank-1 M updates; same layout as chunk_op;
//      writes y directly as bf16 [B*T, C] (fused cast + layout transform)
//   6. final MFMA GEMM y@Wo -> d_out
// Dims: B=4 H=16 T=2048 C=1024 D=64 CS=128 nc=16 N=1024 tokens=8192

#define DEV __device__ __forceinline__

typedef __attribute__((ext_vector_type(4))) float f32x4;
typedef __attribute__((ext_vector_type(8))) __bf16 bf16x8;
typedef __attribute__((ext_vector_type(4))) __bf16 bf16x4;

typedef const __attribute__((address_space(1))) uint32_t* gas1_t;
typedef __attribute__((address_space(3))) uint32_t* las3_t;

DEV void gload_lds16(const void* g, void* l) {
  __builtin_amdgcn_global_load_lds((gas1_t)g, (las3_t)l, 16, 0, 0);
}

DEV float sgm(float x) { return 1.f / (1.f + __expf(-x)); }

// ---- DPP cross-lane helpers (pure VALU, no LDS pipe) ----
template <int CTRL>
DEV float dpp_mov(float x) {
  return __builtin_bit_cast(
      float, __builtin_amdgcn_mov_dpp(__builtin_bit_cast(int, x), CTRL, 0xF, 0xF, true));
}
// sum over 8 contiguous lanes (j = lane&7)
DEV float reduce8(float x) {
  x += dpp_mov<0xB1>(x);   // quad_perm(1,0,3,2) == xor1
  x += dpp_mov<0x4E>(x);   // quad_perm(2,3,0,1) == xor2
  x += dpp_mov<0x141>(x);  // row_half_mirror: quad<->quad within 8-lane half
  return x;
}
// cyclic rotate-reduce: sum over each 16-lane DPP row
DEV float row16_reduce(float x) {
  x += dpp_mov<0x121>(x);  // row_ror:1
  x += dpp_mov<0x122>(x);  // row_ror:2
  x += dpp_mov<0x124>(x);  // row_ror:4
  x += dpp_mov<0x128>(x);  // row_ror:8
  return x;
}

// ---------------- casts ----------------
__global__ __launch_bounds__(256) void cast_f32_bf16(const float* __restrict__ in,
                                                     __bf16* __restrict__ out) {
  int idx = blockIdx.x * 256 + threadIdx.x;
  float4 v = ((const float4*)in)[idx];
  bf16x4 o;
  o[0] = (__bf16)v.x; o[1] = (__bf16)v.y; o[2] = (__bf16)v.z; o[3] = (__bf16)v.w;
  ((bf16x4*)out)[idx] = o;
}

// W [K=1024][N=1024] f32 -> Wt [N][K] bf16
__global__ __launch_bounds__(256) void transpose_cast(const float* __restrict__ W,
                                                      __bf16* __restrict__ Wt) {
  __shared__ float tile[32][33];
  int tx = threadIdx.x & 31, ty = threadIdx.x >> 5;
  int n0 = blockIdx.x * 32, k0 = blockIdx.y * 32;
#pragma unroll
  for (int u = 0; u < 4; ++u)
    tile[ty + u * 8][tx] = W[(size_t)(k0 + ty + u * 8) * 1024 + n0 + tx];
  __syncthreads();
#pragma unroll
  for (int u = 0; u < 4; ++u)
    Wt[(size_t)(n0 + ty + u * 8) * 1024 + k0 + tx] = (__bf16)tile[tx][ty + u * 8];
}

// ---------------- GEMM: C[M=8192,N=1024] = A[M,K=1024] * Bt[N,K]^T ----------------
// 128x128 tile, BK=32, 4 waves, 16x16x32 bf16 MFMA, global_load_lds staging.
// mode 0: C row-major [M,1024]. mode 1: scatter to [B,H,T,D] (row=token, col=h*64+d)
__global__ __launch_bounds__(256) void gemm_bt(const __bf16* __restrict__ A,
                                               const __bf16* __restrict__ Bt,
                                               float* __restrict__ C, int mode) {
  const int t = threadIdx.x;
  const int wv = t >> 6, lane = t & 63;
  const int bm = blockIdx.y, bn = blockIdx.x;
  const int K = 1024;
  __shared__ __bf16 lA[4096];
  __shared__ __bf16 lB[4096];
  f32x4 acc[4][4];
#pragma unroll
  for (int m = 0; m < 4; ++m)
#pragma unroll
    for (int n = 0; n < 4; ++n) acc[m][n] = 0.f;
  const int wr = wv >> 1, wc = wv & 1;
  const int fr = lane & 15, fk = (lane >> 4) * 8;
  const int e0 = (wv * 128 + lane) * 8;
  const int e1 = (wv * 128 + 64 + lane) * 8;
  const int r0s = e0 >> 5, c0s = e0 & 31;
  const int r1s = e1 >> 5, c1s = e1 & 31;
  for (int k0 = 0; k0 < K; k0 += 32) {
    gload_lds16(A + (size_t)(bm * 128 + r0s) * K + k0 + c0s, lA + wv * 1024);
    gload_lds16(Bt + (size_t)(bn * 128 + r0s) * K + k0 + c0s, lB + wv * 1024);
    gload_lds16(A + (size_t)(bm * 128 + r1s) * K + k0 + c1s, lA + wv * 1024 + 512);
    gload_lds16(Bt + (size_t)(bn * 128 + r1s) * K + k0 + c1s, lB + wv * 1024 + 512);
    __syncthreads();
    bf16x8 af[4], bg[4];
#pragma unroll
    for (int m = 0; m < 4; ++m)
      af[m] = *(const bf16x8*)(lA + (wr * 64 + m * 16 + fr) * 32 + fk);
#pragma unroll
    for (int n = 0; n < 4; ++n)
      bg[n] = *(const bf16x8*)(lB + (wc * 64 + n * 16 + fr) * 32 + fk);
#pragma unroll
    for (int m = 0; m < 4; ++m)
#pragma unroll
      for (int n = 0; n < 4; ++n)
        acc[m][n] = __builtin_amdgcn_mfma_f32_16x16x32_bf16(af[m], bg[n], acc[m][n], 0, 0, 0);
    __syncthreads();
  }
  const int rr = (lane >> 4) * 4, cl = lane & 15;
#pragma unroll
  for (int m = 0; m < 4; ++m) {
#pragma unroll
    for (int n = 0; n < 4; ++n) {
#pragma unroll
      for (int rg = 0; rg < 4; ++rg) {
        int row = bm * 128 + wr * 64 + m * 16 + rr + rg;
        int col = bn * 128 + wc * 64 + n * 16 + cl;
        float val = acc[m][n][rg];
        if (mode == 0) {
          C[(size_t)row * 1024 + col] = val;
        } else {
          int b = row >> 11, tk = row & 2047;
          int h = col >> 6, d = col & 63;
          C[(((size_t)b * 16 + h) * 2048 + tk) * 64 + d] = val;
        }
      }
    }
  }
}

// ---------------- per-chunk operator scan (A, B) ----------------
// block = lane n (1024 blocks), 512 threads: thread (i=t>>3, j=t&7) owns
// A[i][j*8..+8), B[i][j*8..+8). k staged+normalized in LDS (DPP row16
// reduce during staging); j-reduce via quad_perm+half_mirror DPP.
__global__ __launch_bounds__(512, 8) void chunk_op(const float* __restrict__ k,
                                                   const float* __restrict__ v,
                                                   const float* __restrict__ ar,
                                                   const float* __restrict__ br,
                                                   float* __restrict__ Aop,
                                                   float* __restrict__ Bop) {
  int n = blockIdx.x, h = (n >> 4) & 15;
  float a = sgm(ar[h]) * 0.5f;
  float b = sgm(br[h]) * 0.5f;
  int t = threadIdx.x, i = t >> 3, j = t & 7;
  __shared__ float ks[8192];
  const float* kc = k + (size_t)n * 8192;
  const float* vc = v + (size_t)n * 8192 + i;
  // stage + normalize: each 16-lane DPP row holds one k-row (16 float4)
#pragma unroll
  for (int it = 0; it < 4; ++it) {
    int u = it * 512 + t;
    float4 kv = ((const float4*)kc)[u];
    float ssq = kv.x * kv.x + kv.y * kv.y + kv.z * kv.z + kv.w * kv.w;
    ssq = row16_reduce(ssq);
    float inv = 1.f / fmaxf(sqrtf(ssq), 1e-12f);
    kv.x *= inv; kv.y *= inv; kv.z *= inv; kv.w *= inv;
    ((float4*)ks)[u] = kv;
  }
  float A[8], B[8];
#pragma unroll
  for (int u = 0; u < 8; ++u) {
    A[u] = (i == j * 8 + u) ? 1.f : 0.f;
    B[u] = 0.f;
  }
  __syncthreads();
  for (int s = 0; s < 128; ++s) {
    float kq[8] __attribute__((aligned(16)));
    *(float4*)(&kq[0]) = *(const float4*)(ks + s * 64 + j * 8);
    *(float4*)(&kq[4]) = *(const float4*)(ks + s * 64 + j * 8 + 4);
    float ak0 = 0.f, ak1 = 0.f, bk0 = 0.f, bk1 = 0.f;
#pragma unroll
    for (int u = 0; u < 4; ++u) { ak0 += A[u] * kq[u]; bk0 += B[u] * kq[u]; }
#pragma unroll
    for (int u = 4; u < 8; ++u) { ak1 += A[u] * kq[u]; bk1 += B[u] * kq[u]; }
    float ak = reduce8(ak0 + ak1);
    float bk = reduce8(bk0 + bk1);
    float vi = vc[s * 64];
    float sA = -a * ak;
    float sB = -a * bk + b * vi;
#pragma unroll
    for (int u = 0; u < 8; ++u) { A[u] += sA * kq[u]; B[u] += sB * kq[u]; }
  }
  size_t base = (size_t)n * 4096 + i * 64 + j * 8;
  *(float4*)(Aop + base) = *(const float4*)(&A[0]);
  *(float4*)(Aop + base + 4) = *(const float4*)(&A[4]);
  *(float4*)(Bop + base) = *(const float4*)(&B[0]);
  *(float4*)(Bop + base + 4) = *(const float4*)(&B[4]);
}

// ---------------- inter-chunk scan: M <- M*A + B ----------------
// 64 blocks (one per (b,h)), sequential over 16 chunks.
__global__ __launch_bounds__(256) void chunk_scan(const float* __restrict__ Aop,
                                                  const float* __restrict__ Bop,
                                                  float* __restrict__ Mstart,
                                                  float* __restrict__ Mfinal) {
  int bh = blockIdx.x;
  int t = threadIdx.x, i = t >> 2, qd = t & 3;
  float M[16] __attribute__((aligned(16)));
#pragma unroll
  for (int j = 0; j < 16; ++j) M[j] = 0.f;
  __shared__ float As[4096];
  for (int c = 0; c < 16; ++c) {
    size_t cb = ((size_t)bh * 16 + c) * 4096;
#pragma unroll
    for (int u = 0; u < 4; ++u)
      *(float4*)(Mstart + cb + i * 64 + qd * 16 + u * 4) = *(const float4*)(&M[u * 4]);
    __syncthreads();
    for (int u = t; u < 1024; u += 256)
      ((float4*)As)[u] = ((const float4*)(Aop + cb))[u];
    __syncthreads();
    float acc[16] __attribute__((aligned(16)));
#pragma unroll
    for (int j = 0; j < 16; ++j) acc[j] = 0.f;
#pragma unroll
    for (int l = 0; l < 64; ++l) {
      float mil = __shfl(M[l & 15], ((t >> 2) & 15) * 4 + (l >> 4), 64);
      const float* arow = As + l * 64 + qd * 16;
#pragma unroll
      for (int j = 0; j < 16; ++j) acc[j] += mil * arow[j];
    }
#pragma unroll
    for (int u = 0; u < 4; ++u) {
      float4 bv = *(const float4*)(Bop + cb + i * 64 + qd * 16 + u * 4);
      acc[u * 4 + 0] += bv.x; acc[u * 4 + 1] += bv.y;
      acc[u * 4 + 2] += bv.z; acc[u * 4 + 3] += bv.w;
    }
#pragma unroll
    for (int j = 0; j < 16; ++j) M[j] = acc[j];
  }
#pragma unroll
  for (int u = 0; u < 4; ++u)
    *(float4*)(Mfinal + (size_t)bh * 4096 + i * 64 + qd * 16 + u * 4) =
        *(const float4*)(&M[u * 4]);
}

// ---------------- intra-chunk application: y_t = M q_t ----------------
// 512 threads: thread (i=t>>3, j=t&7). k staged+normalized in LDS; q,v global.
// y written directly as bf16 [B*T, C]: row = b*2048 + c*128 + s, col = h*64 + i.
__global__ __launch_bounds__(512, 8) void chunk_proc(const float* __restrict__ q,
                                                     const float* __restrict__ k,
                                                     const float* __restrict__ v,
                                                     const float* __restrict__ Mstart,
                                                     const float* __restrict__ ar,
                                                     const float* __restrict__ br,
                                                     __bf16* __restrict__ ybf) {
  int n = blockIdx.x, h = (n >> 4) & 15;
  int b = n >> 8, c = n & 15;
  float a = sgm(ar[h]) * 0.5f;
  float bb = sgm(br[h]) * 0.5f;
  int t = threadIdx.x, i = t >> 3, j = t & 7;
  __shared__ float ks[8192];
  const float* kc = k + (size_t)n * 8192;
  const float* vc = v + (size_t)n * 8192 + i;
  const float* qc = q + (size_t)n * 8192 + j * 8;
  __bf16* yc = ybf + ((size_t)b * 2048 + c * 128) * 1024 + h * 64 + i;
#pragma unroll
  for (int it = 0; it < 4; ++it) {
    int u = it * 512 + t;
    float4 kv = ((const float4*)kc)[u];
    float ssq = kv.x * kv.x + kv.y * kv.y + kv.z * kv.z + kv.w * kv.w;
    ssq = row16_reduce(ssq);
    float inv = 1.f / fmaxf(sqrtf(ssq), 1e-12f);
    kv.x *= inv; kv.y *= inv; kv.z *= inv; kv.w *= inv;
    ((float4*)ks)[u] = kv;
  }
  float M[8];
  {
    const float* mb = Mstart + (size_t)n * 4096 + i * 64 + j * 8;
    *(float4*)(&M[0]) = *(const float4*)(mb);
    *(float4*)(&M[4]) = *(const float4*)(mb + 4);
  }
  __syncthreads();
  for (int s = 0; s < 128; ++s) {
    float kq[8] __attribute__((aligned(16)));
    float qq[8] __attribute__((aligned(16)));
    *(float4*)(&kq[0]) = *(const float4*)(ks + s * 64 + j * 8);
    *(float4*)(&kq[4]) = *(const float4*)(ks + s * 64 + j * 8 + 4);
    *(float4*)(&qq[0]) = *(const float4*)(qc + s * 64);
    *(float4*)(&qq[4]) = *(const float4*)(qc + s * 64 + 4);
    float yp0 = 0.f, yp1 = 0.f, mk0 = 0.f, mk1 = 0.f;
#pragma unroll
    for (int u = 0; u < 4; ++u) { yp0 += M[u] * qq[u]; mk0 += M[u] * kq[u]; }
#pragma unroll
    for (int u = 4; u < 8; ++u) { yp1 += M[u] * qq[u]; mk1 += M[u] * kq[u]; }
    float yp = reduce8(yp0 + yp1);
    float mk = reduce8(mk0 + mk1);
    float vi = vc[s * 64];
    float sc = -a * mk + bb * vi;
#pragma unroll
    for (int u = 0; u < 8; ++u) M[u] += sc * kq[u];
    if (j == 0) yc[(size_t)s * 1024] = (__bf16)yp;
  }
}

extern "C" void kernel_launch(void* const* d_in, const int* in_sizes, int n_in,
                              void* d_out, int out_size, void* d_ws, size_t ws_size,
                              hipStream_t stream) {
  const float* x  = (const float*)d_in[0];
  const float* Wq = (const float*)d_in[1];
  const float* Wk = (const float*)d_in[2];
  const float* Wv = (const float*)d_in[3];
  const float* Wo = (const float*)d_in[4];
  const float* ar = (const float*)d_in[5];
  const float* br = (const float*)d_in[6];

  char* ws = (char*)d_ws;
  __bf16* xb  = (__bf16*)ws;                      // 16 MB (reused later as y_bf16)
  __bf16* wqt = (__bf16*)(ws + (16u << 20));      // 2 MB each
  __bf16* wkt = wqt + (1u << 20);
  __bf16* wvt = wkt + (1u << 20);
  __bf16* wot = wvt + (1u << 20);
  float* qb  = (float*)(ws + (24u << 20));        // 32 MB
  float* kb  = qb + (8u << 20);                   // 32 MB
  float* vb  = kb + (8u << 20);                   // 32 MB
  float* Aop = vb + (8u << 20);                   // 16 MB
  float* Bop = Aop + (4u << 20);                  // 16 MB
  float* Mst = Bop + (4u << 20);                  // 16 MB
  __bf16* ybf = xb;                               // reuse x_bf16 region

  float* yout = (float*)d_out;                    // [B*T, C] = 8,388,608 f32
  float* Mfin = yout + 8388608;                   // [B,H,D,D] = 262,144 f32

  cast_f32_bf16<<<8192, 256, 0, stream>>>(x, xb);
  dim3 tg(32, 32);
  transpose_cast<<<tg, 256, 0, stream>>>(Wq, wqt);
  transpose_cast<<<tg, 256, 0, stream>>>(Wk, wkt);
  transpose_cast<<<tg, 256, 0, stream>>>(Wv, wvt);
  transpose_cast<<<tg, 256, 0, stream>>>(Wo, wot);

  dim3 gg(8, 64);
  gemm_bt<<<gg, 256, 0, stream>>>(xb, wqt, qb, 1);
  gemm_bt<<<gg, 256, 0, stream>>>(xb, wkt, kb, 1);
  gemm_bt<<<gg, 256, 0, stream>>>(xb, wvt, vb, 1);

  chunk_op<<<1024, 512, 0, stream>>>(kb, vb, ar, br, Aop, Bop);
  chunk_scan<<<64, 256, 0, stream>>>(Aop, Bop, Mst, Mfin);
  chunk_proc<<<1024, 512, 0, stream>>>(qb, kb, vb, Mst, ar, br, ybf);

  gemm_bt<<<gg, 256, 0, stream>>>(ybf, wot, yout, 0);
}